// Round 2
// baseline (1231.717 us; speedup 1.0000x reference)
//
#include <hip/hip_runtime.h>

#define NNODES 8192
#define KN 32
#define CC 16
#define HD 64

typedef unsigned short bf16_t;

__device__ __forceinline__ float bf2f(unsigned short u) {
    union { unsigned int i; float f; } v; v.i = ((unsigned int)u) << 16; return v.f;
}
__device__ __forceinline__ unsigned short f2bf(float f) {
    union { float ff; unsigned int i; } v; v.ff = f;
    unsigned int r = v.i + 0x7FFFu + ((v.i >> 16) & 1u);
    return (unsigned short)(r >> 16);
}
__device__ __forceinline__ float4 bf2f4(ushort4 u) {
    float4 r; r.x = bf2f(u.x); r.y = bf2f(u.y); r.z = bf2f(u.z); r.w = bf2f(u.w); return r;
}
__device__ __forceinline__ float silu_f(float x) {
    return x / (1.0f + __expf(-x));
}

template<bool F32>
__device__ __forceinline__ float ldf(const void* p, int i) {
    if constexpr (F32) return ((const float*)p)[i];
    else               return bf2f(((const unsigned short*)p)[i]);
}
template<bool F32>
__device__ __forceinline__ float4 ldf4(const void* p, int quad) {  // elements [4q..4q+3]
    if constexpr (F32) return ((const float4*)p)[quad];
    else               return bf2f4(((const ushort4*)p)[quad]);
}
template<bool F32>
__device__ __forceinline__ void stf(void* p, int i, float v) {
    if constexpr (F32) ((float*)p)[i] = v;
    else               ((unsigned short*)p)[i] = f2bf(v);
}

struct Smem {
    float rbf[KN][16];      // 512
    float e[KN][4];         // 128
    float f0n[KN][CC];      // 512
    float f1n[KN][CC][3];   // 1536
    float h1[KN][HD];       // 2048 (aliased by red[768]+S[64] in phases e/f)
    float h2[KN][HD];       // 2048
    float con[KN][CC][4];   // 2048
    float G[CC][4][HD];     // 4096
    float out0[CC];
    float out1[CC][3];
    float f0self[CC];
    float f1self[CC][3];
    float f0g[CC];
    float fac1[CC];
    int   flags[2];
};

template<bool F32, bool I64>
__device__ void gttfn_body(Smem& sm,
                           const void* f0,  const void* f1,
                           const void* rbf, const void* gte,
                           const void* W1,  const void* b1,
                           const void* W2,  const void* b2,
                           const void* W3,  const void* b3,
                           const void* lg0, const void* lb0,
                           const void* lg1, const void* lb1,
                           const void* gW0, const void* gb0,
                           const void* gW1, const void* gb1,
                           const void* rW0, const void* rW1,
                           const int* __restrict__ nbr,
                           void* out)
{
    const int tid = threadIdx.x;
    const int n   = blockIdx.x;

    float* s_red = &sm.h1[0][0];          // [16 seg][16 o][3 d] = 768
    float* s_S   = &sm.h1[0][0] + 768;    // [16 c][4]

    // ---- load node-local data ----
    for (int i = tid; i < KN*16; i += 256)
        ((float*)sm.rbf)[i] = ldf<F32>(rbf, n*KN*16 + i);
    if (tid < KN*4)
        ((float*)sm.e)[tid] = ldf<F32>(gte, n*KN*4 + tid);
    for (int idx = tid; idx < KN*CC; idx += 256) {
        int j = idx >> 4, c = idx & 15;
        int nb = I64 ? nbr[2*(n*KN + j)] : nbr[n*KN + j];
        sm.f0n[j][c] = ldf<F32>(f0, nb*CC + c);
        int base = (nb*CC + c)*3;
        sm.f1n[j][c][0] = ldf<F32>(f1, base+0);
        sm.f1n[j][c][1] = ldf<F32>(f1, base+1);
        sm.f1n[j][c][2] = ldf<F32>(f1, base+2);
    }
    if (tid < CC) { sm.f0self[tid] = ldf<F32>(f0, n*CC + tid); sm.out0[tid] = 0.f; }
    else if (tid < CC + 48) {
        int k = tid - CC;
        ((float*)sm.f1self)[k] = ldf<F32>(f1, n*CC*3 + k);
        ((float*)sm.out1)[k] = 0.f;
    }
    __syncthreads();

    const int dot_arr[5] = {1,3,3,1,3};
    const int ot_arr[5]  = {0,1,1,0,1};

    for (int t = 0; t < 5; ++t) {
        const int dt = dot_arr[t];

        // ---- (a) contracted[j][c][d] ----
        for (int idx = tid; idx < KN*CC; idx += 256) {
            int j = idx >> 4, c = idx & 15;
            float e0v = sm.e[j][0];
            float ex = sm.e[j][1], ey = sm.e[j][2], ez = sm.e[j][3];
            if (t == 0) {
                sm.con[j][c][0] = e0v * sm.f0n[j][c];
            } else if (t == 1) {
                float fv = sm.f0n[j][c];
                sm.con[j][c][0] = ex*fv; sm.con[j][c][1] = ey*fv; sm.con[j][c][2] = ez*fv;
            } else if (t == 2) {
                sm.con[j][c][0] = e0v*sm.f1n[j][c][0];
                sm.con[j][c][1] = e0v*sm.f1n[j][c][1];
                sm.con[j][c][2] = e0v*sm.f1n[j][c][2];
            } else if (t == 3) {
                sm.con[j][c][0] = ex*sm.f1n[j][c][0] + ey*sm.f1n[j][c][1] + ez*sm.f1n[j][c][2];
            } else {
                float fx = sm.f1n[j][c][0], fy = sm.f1n[j][c][1], fz = sm.f1n[j][c][2];
                sm.con[j][c][0] = fy*ez - fz*ey;
                sm.con[j][c][1] = fz*ex - fx*ez;
                sm.con[j][c][2] = fx*ey - fy*ex;
            }
        }

        // ---- (b) layer1: h1 = silu(rbf @ W1[t] + b1[t]) ----
        for (int task = tid; task < KN*16; task += 256) {
            int j = task >> 4, hq = task & 15;
            float4 acc = ldf4<F32>(b1, t*16 + hq);
            const float4* rrow = (const float4*)(&sm.rbf[j][0]);
            #pragma unroll
            for (int r4 = 0; r4 < 4; ++r4) {
                float4 rv = rrow[r4];
                float4 w0 = ldf4<F32>(W1, t*256 + (r4*4+0)*16 + hq);
                float4 w1 = ldf4<F32>(W1, t*256 + (r4*4+1)*16 + hq);
                float4 w2 = ldf4<F32>(W1, t*256 + (r4*4+2)*16 + hq);
                float4 w3 = ldf4<F32>(W1, t*256 + (r4*4+3)*16 + hq);
                acc.x += rv.x*w0.x + rv.y*w1.x + rv.z*w2.x + rv.w*w3.x;
                acc.y += rv.x*w0.y + rv.y*w1.y + rv.z*w2.y + rv.w*w3.y;
                acc.z += rv.x*w0.z + rv.y*w1.z + rv.z*w2.z + rv.w*w3.z;
                acc.w += rv.x*w0.w + rv.y*w1.w + rv.z*w2.w + rv.w*w3.w;
            }
            float4 r;
            r.x = silu_f(acc.x); r.y = silu_f(acc.y);
            r.z = silu_f(acc.z); r.w = silu_f(acc.w);
            ((float4*)&sm.h1[j][0])[hq] = r;
        }
        __syncthreads();

        // ---- (c) layer2: h2 = silu(h1 @ W2[t] + b2[t]) ----
        for (int task = tid; task < KN*16; task += 256) {
            int j = task >> 4, hq = task & 15;
            float4 acc = ldf4<F32>(b2, t*16 + hq);
            const float4* h1row = (const float4*)(&sm.h1[j][0]);
            #pragma unroll 4
            for (int h4 = 0; h4 < 16; ++h4) {
                float4 hv = h1row[h4];
                float4 w0 = ldf4<F32>(W2, t*1024 + (h4*4+0)*16 + hq);
                float4 w1 = ldf4<F32>(W2, t*1024 + (h4*4+1)*16 + hq);
                float4 w2 = ldf4<F32>(W2, t*1024 + (h4*4+2)*16 + hq);
                float4 w3 = ldf4<F32>(W2, t*1024 + (h4*4+3)*16 + hq);
                acc.x += hv.x*w0.x + hv.y*w1.x + hv.z*w2.x + hv.w*w3.x;
                acc.y += hv.x*w0.y + hv.y*w1.y + hv.z*w2.y + hv.w*w3.y;
                acc.z += hv.x*w0.z + hv.y*w1.z + hv.z*w2.z + hv.w*w3.z;
                acc.w += hv.x*w0.w + hv.y*w1.w + hv.z*w2.w + hv.w*w3.w;
            }
            float4 r;
            r.x = silu_f(acc.x); r.y = silu_f(acc.y);
            r.z = silu_f(acc.z); r.w = silu_f(acc.w);
            ((float4*)&sm.h2[j][0])[hq] = r;
        }
        __syncthreads();

        // ---- (d) G[h,c,d] = sum_j h2[j,h]*con[j,c,d]; S[c,d]=sum_j con ----
        {
            int hq = tid & 15, c = tid >> 4;
            float4 g0 = make_float4(0,0,0,0), g1 = g0, g2 = g0;
            float sx = 0, sy = 0, sz = 0;
            if (dt == 1) {
                #pragma unroll 4
                for (int j = 0; j < KN; ++j) {
                    float4 h2q = ((const float4*)&sm.h2[j][0])[hq];
                    float cv = sm.con[j][c][0];
                    g0.x += h2q.x*cv; g0.y += h2q.y*cv;
                    g0.z += h2q.z*cv; g0.w += h2q.w*cv;
                    sx += cv;
                }
            } else {
                #pragma unroll 4
                for (int j = 0; j < KN; ++j) {
                    float4 h2q = ((const float4*)&sm.h2[j][0])[hq];
                    float4 cv = *((const float4*)&sm.con[j][c][0]);
                    g0.x += h2q.x*cv.x; g0.y += h2q.y*cv.x; g0.z += h2q.z*cv.x; g0.w += h2q.w*cv.x;
                    g1.x += h2q.x*cv.y; g1.y += h2q.y*cv.y; g1.z += h2q.z*cv.y; g1.w += h2q.w*cv.y;
                    g2.x += h2q.x*cv.z; g2.y += h2q.y*cv.z; g2.z += h2q.z*cv.z; g2.w += h2q.w*cv.z;
                    sx += cv.x; sy += cv.y; sz += cv.z;
                }
            }
            ((float4*)&sm.G[c][0][0])[hq] = g0;
            if (dt == 3) {
                ((float4*)&sm.G[c][1][0])[hq] = g1;
                ((float4*)&sm.G[c][2][0])[hq] = g2;
            }
            if (hq == 0) { s_S[c*4+0] = sx; s_S[c*4+1] = sy; s_S[c*4+2] = sz; }
        }
        __syncthreads();

        // ---- (e) msg partials over hc-segments ----
        {
            int o = tid & 15, seg = tid >> 4;
            float a0 = 0, a1 = 0, a2 = 0;
            int hc0 = seg*64;
            #pragma unroll 4
            for (int m = 0; m < 64; ++m) {
                int hc = hc0 + m;
                int h = hc >> 4, c = hc & 15;
                float w = ldf<F32>(W3, t*16384 + h*256 + c*16 + o);
                a0 += w * sm.G[c][0][h];
                if (dt == 3) { a1 += w * sm.G[c][1][h]; a2 += w * sm.G[c][2][h]; }
            }
            if (seg == 0) {
                for (int c2 = 0; c2 < 16; ++c2) {
                    float b = ldf<F32>(b3, t*256 + c2*16 + o);
                    a0 += b * s_S[c2*4+0];
                    if (dt == 3) { a1 += b * s_S[c2*4+1]; a2 += b * s_S[c2*4+2]; }
                }
            }
            s_red[(seg*16+o)*3 + 0] = a0;
            if (dt == 3) { s_red[(seg*16+o)*3 + 1] = a1; s_red[(seg*16+o)*3 + 2] = a2; }
        }
        __syncthreads();

        // ---- (f) reduce segments ----
        if (tid < 16*dt) {
            int o = tid & 15, d = tid >> 4;
            float sum = 0;
            #pragma unroll
            for (int seg = 0; seg < 16; ++seg) sum += s_red[(seg*16+o)*3 + d];
            if (ot_arr[t] == 0) sm.out0[o] += sum;
            else                sm.out1[o][d] += sum;
        }
        __syncthreads();
    }

    // ---- epilogue ----
    if (tid < 32) {
        if (tid < 16) {
            int c = tid;
            float v = sm.out0[c];
            float nrm = fmaxf(fabsf(v), 1e-8f);
            float mu = nrm;
            #pragma unroll
            for (int m = 8; m >= 1; m >>= 1) mu += __shfl_xor(mu, m, 16);
            mu *= (1.0f/16.0f);
            float dl = nrm - mu;
            float var = dl*dl;
            #pragma unroll
            for (int m = 8; m >= 1; m >>= 1) var += __shfl_xor(var, m, 16);
            var *= (1.0f/16.0f);
            float scaled = dl / sqrtf(var + 1e-5f) * ldf<F32>(lg0, c) + ldf<F32>(lb0, c);
            sm.f0g[c] = v / nrm * scaled;
        } else {
            int c = tid - 16;
            float x = sm.out1[c][0], y = sm.out1[c][1], z = sm.out1[c][2];
            float nrm = fmaxf(sqrtf(x*x + y*y + z*z), 1e-8f);
            float mu = nrm;
            #pragma unroll
            for (int m = 8; m >= 1; m >>= 1) mu += __shfl_xor(mu, m, 16);
            mu *= (1.0f/16.0f);
            float dl = nrm - mu;
            float var = dl*dl;
            #pragma unroll
            for (int m = 8; m >= 1; m >>= 1) var += __shfl_xor(var, m, 16);
            var *= (1.0f/16.0f);
            float scaled = dl / sqrtf(var + 1e-5f) * ldf<F32>(lg1, c) + ldf<F32>(lb1, c);
            sm.fac1[c] = scaled / nrm;
        }
    }
    __syncthreads();
    if (tid < 16) {
        int o = tid;
        float a0 = ldf<F32>(gb0, o), a1 = ldf<F32>(gb1, o);
        float r0 = 0, rx = 0, ry = 0, rz = 0;
        #pragma unroll 4
        for (int c = 0; c < 16; ++c) {
            float fg = sm.f0g[c];
            a0 += fg * ldf<F32>(gW0, c*16+o);
            a1 += fg * ldf<F32>(gW1, c*16+o);
            r0 += sm.f0self[c] * ldf<F32>(rW0, c*16+o);
            float rw1 = ldf<F32>(rW1, c*16+o);
            rx += sm.f1self[c][0]*rw1; ry += sm.f1self[c][1]*rw1; rz += sm.f1self[c][2]*rw1;
        }
        float g0v = 1.f/(1.f + __expf(-a0));
        float g1v = 1.f/(1.f + __expf(-a1));
        stf<F32>(out, n*16 + o, sm.f0g[o]*g0v + r0);
        int b = NNODES*CC + (n*16 + o)*3;
        float fac = sm.fac1[o]*g1v;
        stf<F32>(out, b+0, sm.out1[o][0]*fac + rx);
        stf<F32>(out, b+1, sm.out1[o][1]*fac + ry);
        stf<F32>(out, b+2, sm.out1[o][2]*fac + rz);
    }
}

__global__ __launch_bounds__(256)
void gttfn_kernel(const void* f0,  const void* f1,
                  const void* rbf, const void* gte,
                  const void* W1,  const void* b1,
                  const void* W2,  const void* b2,
                  const void* W3,  const void* b3,
                  const void* lg0, const void* lb0,
                  const void* lg1, const void* lb1,
                  const void* gW0, const void* gb0,
                  const void* gW1, const void* gb1,
                  const void* rW0, const void* rW1,
                  const void* nbr_v,
                  void* out)
{
    __shared__ Smem sm;
    const int tid = threadIdx.x;

    // ---- dtype detection (uniform across grid, deterministic) ----
    if (tid < 64) {
        const unsigned short* u = (const unsigned short*)f0;
        bool garbage = false;
        {   // if f0 is fp32, even-indexed ushorts are low-mantissa noise
            unsigned short w = u[2*tid];
            int e = (w >> 7) & 0xFF;
            garbage = (e >= 0x83) || (e <= 0x30);
        }
        bool isF32 = __any(garbage);
        const int* ni = (const int*)nbr_v;
        bool hi_nonzero = (tid < 32) ? (ni[2*tid+1] != 0) : false;
        bool isI64 = !__any(hi_nonzero);
        if (tid == 0) { sm.flags[0] = isF32 ? 1 : 0; sm.flags[1] = isI64 ? 1 : 0; }
    }
    __syncthreads();
    int fF32 = sm.flags[0], fI64 = sm.flags[1];
    __syncthreads();   // flags consumed; body reuses sm

    const int* nbr = (const int*)nbr_v;
    if (fF32) {
        if (fI64) gttfn_body<true, true >(sm, f0,f1,rbf,gte,W1,b1,W2,b2,W3,b3,lg0,lb0,lg1,lb1,gW0,gb0,gW1,gb1,rW0,rW1,nbr,out);
        else      gttfn_body<true, false>(sm, f0,f1,rbf,gte,W1,b1,W2,b2,W3,b3,lg0,lb0,lg1,lb1,gW0,gb0,gW1,gb1,rW0,rW1,nbr,out);
    } else {
        if (fI64) gttfn_body<false, true >(sm, f0,f1,rbf,gte,W1,b1,W2,b2,W3,b3,lg0,lb0,lg1,lb1,gW0,gb0,gW1,gb1,rW0,rW1,nbr,out);
        else      gttfn_body<false, false>(sm, f0,f1,rbf,gte,W1,b1,W2,b2,W3,b3,lg0,lb0,lg1,lb1,gW0,gb0,gW1,gb1,rW0,rW1,nbr,out);
    }
}

extern "C" void kernel_launch(void* const* d_in, const int* in_sizes, int n_in,
                              void* d_out, int out_size, void* d_ws, size_t ws_size,
                              hipStream_t stream) {
    gttfn_kernel<<<dim3(NNODES), dim3(256), 0, stream>>>(
        d_in[0],  d_in[1],  d_in[2],  d_in[3],
        d_in[4],  d_in[5],  d_in[6],  d_in[7],
        d_in[8],  d_in[9],  d_in[10], d_in[11],
        d_in[12], d_in[13], d_in[14], d_in[15],
        d_in[16], d_in[17], d_in[18], d_in[19],
        d_in[20], d_out);
}

// Round 7
// 733.407 us; speedup vs baseline: 1.6794x; 1.6794x over previous
//
#include <hip/hip_runtime.h>

#define NNODES 8192
#define KN 32
#define CC 16
#define HD 64

typedef unsigned short u16;

__device__ __forceinline__ float bf2f(u16 u) {
    union { unsigned int i; float f; } v; v.i = ((unsigned int)u) << 16; return v.f;
}
__device__ __forceinline__ u16 f2bf(float f) {
    union { float ff; unsigned int i; } v; v.ff = f;
    unsigned int r = v.i + 0x7FFFu + ((v.i >> 16) & 1u);
    return (u16)(r >> 16);
}
__device__ __forceinline__ float4 bf2f4(ushort4 u) {
    float4 r; r.x = bf2f(u.x); r.y = bf2f(u.y); r.z = bf2f(u.z); r.w = bf2f(u.w); return r;
}
__device__ __forceinline__ float silu_f(float x) { return x / (1.0f + __expf(-x)); }

template<bool F32>
__device__ __forceinline__ float ldf(const void* p, int i) {
    if constexpr (F32) return ((const float*)p)[i];
    else               return bf2f(((const u16*)p)[i]);
}
template<bool F32>
__device__ __forceinline__ float4 ldx4(const void* p, int i) {  // elements i..i+3, i%4==0
    if constexpr (F32) return ((const float4*)p)[i >> 2];
    else               return bf2f4(((const ushort4*)p)[i >> 2]);
}
template<bool F32>
__device__ __forceinline__ void stf(void* p, int i, float v) {
    if constexpr (F32) ((float*)p)[i] = v;
    else               ((u16*)p)[i] = f2bf(v);
}

struct __align__(16) Smem {
    union {
        float W2s[HD * HD];                                  // 16384 B, live stage->C
        struct { float G[3][16][68]; float red[4][16][3]; } g;  // live D->F (13824 B)
    } u;
    float rbf[KN][16];       // 2048
    float e[KN][4];          // 512
    float f0n[KN][CC];       // 2048
    float f1n[KN][CC][3];    // 6144
    float con[KN][CC][4];    // 8192  (fp32! d padded to 4)
    float h1[KN][68];        // 8704  (row padded 64->68)
    float h2[KN][68];        // 8704
    float S[3][CC];          // 192
    float out0[CC];
    float out1[CC][3];
    float f0self[CC];
    float f1self[CC][3];
    float f0g[CC];
    float fac1[CC];
};   // ~53.6 KB -> 3 blocks/CU

template<bool F32, bool I64>
__device__ void gttfn_body(Smem& sm,
                           const void* f0,  const void* f1,
                           const void* rbf, const void* gte,
                           const void* W1,  const void* b1,
                           const void* W2,  const void* b2,
                           const void* W3,  const void* b3,
                           const void* lg0, const void* lb0,
                           const void* lg1, const void* lb1,
                           const void* gW0, const void* gb0,
                           const void* gW1, const void* gb1,
                           const void* rW0, const void* rW1,
                           const int* __restrict__ nbr,
                           void* out)
{
    const int tid  = threadIdx.x;
    const int n    = blockIdx.x;
    const int lane = tid & 63;
    const int wv   = tid >> 6;

    // ---- preamble (round-2-verified) ----
    for (int i = tid; i < KN * 16; i += 256)
        ((float*)sm.rbf)[i] = ldf<F32>(rbf, n * KN * 16 + i);
    if (tid < KN * 4)
        ((float*)sm.e)[tid] = ldf<F32>(gte, n * KN * 4 + tid);
    for (int idx = tid; idx < KN * CC; idx += 256) {
        int j = idx >> 4, c = idx & 15;
        int nb = I64 ? nbr[2 * (n * KN + j)] : nbr[n * KN + j];
        sm.f0n[j][c] = ldf<F32>(f0, nb * CC + c);
        int base = (nb * CC + c) * 3;
        sm.f1n[j][c][0] = ldf<F32>(f1, base + 0);
        sm.f1n[j][c][1] = ldf<F32>(f1, base + 1);
        sm.f1n[j][c][2] = ldf<F32>(f1, base + 2);
    }
    if (tid < CC) { sm.f0self[tid] = ldf<F32>(f0, n * CC + tid); sm.out0[tid] = 0.f; }
    else if (tid < CC + 48) {
        int k = tid - CC;
        ((float*)sm.f1self)[k] = ldf<F32>(f1, n * CC * 3 + k);
        ((float*)sm.out1)[k] = 0.f;
    }
    __syncthreads();

    const int dot_arr[5] = {1, 3, 3, 1, 3};
    const int ot_arr[5]  = {0, 1, 1, 0, 1};

    for (int t = 0; t < 5; ++t) {
        const int dt = dot_arr[t];

        // ---- phase A (round-2 text): con fp32 ----
        for (int idx = tid; idx < KN * CC; idx += 256) {
            int j = idx >> 4, c = idx & 15;
            float e0v = sm.e[j][0];
            float ex = sm.e[j][1], ey = sm.e[j][2], ez = sm.e[j][3];
            if (t == 0) {
                sm.con[j][c][0] = e0v * sm.f0n[j][c];
            } else if (t == 1) {
                float fv = sm.f0n[j][c];
                sm.con[j][c][0] = ex * fv; sm.con[j][c][1] = ey * fv; sm.con[j][c][2] = ez * fv;
            } else if (t == 2) {
                sm.con[j][c][0] = e0v * sm.f1n[j][c][0];
                sm.con[j][c][1] = e0v * sm.f1n[j][c][1];
                sm.con[j][c][2] = e0v * sm.f1n[j][c][2];
            } else if (t == 3) {
                sm.con[j][c][0] = ex * sm.f1n[j][c][0] + ey * sm.f1n[j][c][1]
                                + ez * sm.f1n[j][c][2];
            } else {
                float fx = sm.f1n[j][c][0], fy = sm.f1n[j][c][1], fz = sm.f1n[j][c][2];
                sm.con[j][c][0] = fy * ez - fz * ey;
                sm.con[j][c][1] = fz * ex - fx * ez;
                sm.con[j][c][2] = fx * ey - fy * ex;
            }
        }

        // ---- stage W2[t] -> LDS fp32 (32x reuse in phase C) ----
        for (int i = tid; i < 1024; i += 256) {
            float4 w = ldx4<F32>(W2, t * 4096 + i * 4);
            *(float4*)&sm.u.W2s[i * 4] = w;
        }

        // ---- phase B (round-2 text): h1 = silu(rbf @ W1 + b1), fp32 ----
        for (int task = tid; task < KN * 16; task += 256) {
            int j = task >> 4, hq = task & 15;
            float4 acc = ldx4<F32>(b1, t * 64 + hq * 4);
            const float4* rrow = (const float4*)(&sm.rbf[j][0]);
#pragma unroll
            for (int r4 = 0; r4 < 4; ++r4) {
                float4 rv = rrow[r4];
                float4 w0 = ldx4<F32>(W1, t * 1024 + (r4 * 4 + 0) * 64 + hq * 4);
                float4 w1 = ldx4<F32>(W1, t * 1024 + (r4 * 4 + 1) * 64 + hq * 4);
                float4 w2 = ldx4<F32>(W1, t * 1024 + (r4 * 4 + 2) * 64 + hq * 4);
                float4 w3 = ldx4<F32>(W1, t * 1024 + (r4 * 4 + 3) * 64 + hq * 4);
                acc.x += rv.x * w0.x + rv.y * w1.x + rv.z * w2.x + rv.w * w3.x;
                acc.y += rv.x * w0.y + rv.y * w1.y + rv.z * w2.y + rv.w * w3.y;
                acc.z += rv.x * w0.z + rv.y * w1.z + rv.z * w2.z + rv.w * w3.z;
                acc.w += rv.x * w0.w + rv.y * w1.w + rv.z * w2.w + rv.w * w3.w;
            }
            float4 r;
            r.x = silu_f(acc.x); r.y = silu_f(acc.y);
            r.z = silu_f(acc.z); r.w = silu_f(acc.w);
            *(float4*)&sm.h1[j][hq * 4] = r;
        }
        __syncthreads();

        // ---- phase C: h2 = silu(h1 @ W2s + b2), fp32, W2 from LDS ----
        for (int task = tid; task < KN * 16; task += 256) {
            int j = task >> 4, hq = task & 15;
            float4 acc = ldx4<F32>(b2, t * 64 + hq * 4);
#pragma unroll 4
            for (int h4 = 0; h4 < 16; ++h4) {
                float4 hv = *(const float4*)&sm.h1[j][h4 * 4];
                const float* Wr = &sm.u.W2s[(h4 * 4) * 64 + hq * 4];
                float4 w0 = *(const float4*)(Wr);
                float4 w1 = *(const float4*)(Wr + 64);
                float4 w2 = *(const float4*)(Wr + 128);
                float4 w3 = *(const float4*)(Wr + 192);
                acc.x += hv.x * w0.x + hv.y * w1.x + hv.z * w2.x + hv.w * w3.x;
                acc.y += hv.x * w0.y + hv.y * w1.y + hv.z * w2.y + hv.w * w3.y;
                acc.z += hv.x * w0.z + hv.y * w1.z + hv.z * w2.z + hv.w * w3.z;
                acc.w += hv.x * w0.w + hv.y * w1.w + hv.z * w2.w + hv.w * w3.w;
            }
            float4 r;
            r.x = silu_f(acc.x); r.y = silu_f(acc.y);
            r.z = silu_f(acc.z); r.w = silu_f(acc.w);
            *(float4*)&sm.h2[j][hq * 4] = r;
        }
        __syncthreads();

        // ---- phase D (round-2 text): G[d][c][h] + S, fp32 ----
        {
            int hq = tid & 15, c = tid >> 4;
            float4 g0 = make_float4(0, 0, 0, 0), g1 = g0, g2 = g0;
            float sx = 0, sy = 0, sz = 0;
            if (dt == 1) {
#pragma unroll 4
                for (int j = 0; j < KN; ++j) {
                    float4 h2q = *(const float4*)&sm.h2[j][hq * 4];
                    float cv = sm.con[j][c][0];
                    g0.x += h2q.x * cv; g0.y += h2q.y * cv;
                    g0.z += h2q.z * cv; g0.w += h2q.w * cv;
                    sx += cv;
                }
            } else {
#pragma unroll 4
                for (int j = 0; j < KN; ++j) {
                    float4 h2q = *(const float4*)&sm.h2[j][hq * 4];
                    float4 cv = *(const float4*)&sm.con[j][c][0];
                    g0.x += h2q.x * cv.x; g0.y += h2q.y * cv.x; g0.z += h2q.z * cv.x; g0.w += h2q.w * cv.x;
                    g1.x += h2q.x * cv.y; g1.y += h2q.y * cv.y; g1.z += h2q.z * cv.y; g1.w += h2q.w * cv.y;
                    g2.x += h2q.x * cv.z; g2.y += h2q.y * cv.z; g2.z += h2q.z * cv.z; g2.w += h2q.w * cv.z;
                    sx += cv.x; sy += cv.y; sz += cv.z;
                }
            }
            *(float4*)&sm.u.g.G[0][c][hq * 4] = g0;
            if (dt == 3) {
                *(float4*)&sm.u.g.G[1][c][hq * 4] = g1;
                *(float4*)&sm.u.g.G[2][c][hq * 4] = g2;
            }
            if (hq == 0) {
                sm.S[0][c] = sx;
                if (dt == 3) { sm.S[1][c] = sy; sm.S[2][c] = sz; }
            }
        }
        __syncthreads();

        // ---- phase E: vectorized W3, in-wave shuffle reduce over h ----
        {
            const int h = tid >> 2, o4 = tid & 3;
            float acc[3][4] = {{0,0,0,0},{0,0,0,0},{0,0,0,0}};
#pragma unroll 4
            for (int c = 0; c < 16; ++c) {
                float4 wq = ldx4<F32>(W3, t * 16384 + h * 256 + c * 16 + o4 * 4);
                float g0v = sm.u.g.G[0][c][h];
                acc[0][0] += g0v * wq.x; acc[0][1] += g0v * wq.y;
                acc[0][2] += g0v * wq.z; acc[0][3] += g0v * wq.w;
                if (dt == 3) {
                    float g1v = sm.u.g.G[1][c][h];
                    float g2v = sm.u.g.G[2][c][h];
                    acc[1][0] += g1v * wq.x; acc[1][1] += g1v * wq.y;
                    acc[1][2] += g1v * wq.z; acc[1][3] += g1v * wq.w;
                    acc[2][0] += g2v * wq.x; acc[2][1] += g2v * wq.y;
                    acc[2][2] += g2v * wq.z; acc[2][3] += g2v * wq.w;
                }
            }
            // reduce over the wave's 16 h values (lane bits 2..5)
#pragma unroll
            for (int m = 4; m <= 32; m <<= 1) {
#pragma unroll
                for (int d = 0; d < 3; ++d) {
                    if (d < dt) {
#pragma unroll
                        for (int oo = 0; oo < 4; ++oo)
                            acc[d][oo] += __shfl_xor(acc[d][oo], m);
                    }
                }
            }
            if (lane < 4) {
#pragma unroll
                for (int d = 0; d < 3; ++d) {
                    if (d < dt) {
#pragma unroll
                        for (int oo = 0; oo < 4; ++oo)
                            sm.u.g.red[wv][lane * 4 + oo][d] = acc[d][oo];
                    }
                }
            }
        }
        __syncthreads();

        // ---- phase F: combine wave partials + b3*S ----
        if (tid < 16 * dt) {
            int o = tid & 15, d = tid >> 4;
            float s = sm.u.g.red[0][o][d] + sm.u.g.red[1][o][d]
                    + sm.u.g.red[2][o][d] + sm.u.g.red[3][o][d];
#pragma unroll 4
            for (int c = 0; c < 16; ++c)
                s += ldf<F32>(b3, t * 256 + c * 16 + o) * sm.S[d][c];
            if (ot_arr[t] == 0) sm.out0[o] += s;
            else                sm.out1[o][d] += s;
        }
        __syncthreads();
    }

    // ---- epilogue (round-2-verified) ----
    if (tid < 32) {
        if (tid < 16) {
            int c = tid;
            float v = sm.out0[c];
            float nrm = fmaxf(fabsf(v), 1e-8f);
            float mu = nrm;
#pragma unroll
            for (int m = 8; m >= 1; m >>= 1) mu += __shfl_xor(mu, m, 16);
            mu *= (1.0f / 16.0f);
            float dl = nrm - mu;
            float var = dl * dl;
#pragma unroll
            for (int m = 8; m >= 1; m >>= 1) var += __shfl_xor(var, m, 16);
            var *= (1.0f / 16.0f);
            float scaled = dl / sqrtf(var + 1e-5f) * ldf<F32>(lg0, c) + ldf<F32>(lb0, c);
            sm.f0g[c] = v / nrm * scaled;
        } else {
            int c = tid - 16;
            float x = sm.out1[c][0], y = sm.out1[c][1], z = sm.out1[c][2];
            float nrm = fmaxf(sqrtf(x * x + y * y + z * z), 1e-8f);
            float mu = nrm;
#pragma unroll
            for (int m = 8; m >= 1; m >>= 1) mu += __shfl_xor(mu, m, 16);
            mu *= (1.0f / 16.0f);
            float dl = nrm - mu;
            float var = dl * dl;
#pragma unroll
            for (int m = 8; m >= 1; m >>= 1) var += __shfl_xor(var, m, 16);
            var *= (1.0f / 16.0f);
            float scaled = dl / sqrtf(var + 1e-5f) * ldf<F32>(lg1, c) + ldf<F32>(lb1, c);
            sm.fac1[c] = scaled / nrm;
        }
    }
    __syncthreads();
    if (tid < 16) {
        int o = tid;
        float a0 = ldf<F32>(gb0, o), a1 = ldf<F32>(gb1, o);
        float r0 = 0, rx = 0, ry = 0, rz = 0;
#pragma unroll 4
        for (int c = 0; c < 16; ++c) {
            float fg = sm.f0g[c];
            a0 += fg * ldf<F32>(gW0, c * 16 + o);
            a1 += fg * ldf<F32>(gW1, c * 16 + o);
            r0 += sm.f0self[c] * ldf<F32>(rW0, c * 16 + o);
            float rw1 = ldf<F32>(rW1, c * 16 + o);
            rx += sm.f1self[c][0] * rw1; ry += sm.f1self[c][1] * rw1; rz += sm.f1self[c][2] * rw1;
        }
        float g0v = 1.f / (1.f + __expf(-a0));
        float g1v = 1.f / (1.f + __expf(-a1));
        stf<F32>(out, n * 16 + o, sm.f0g[o] * g0v + r0);
        int b = NNODES * CC + (n * 16 + o) * 3;
        float fac = sm.fac1[o] * g1v;
        stf<F32>(out, b + 0, sm.out1[o][0] * fac + rx);
        stf<F32>(out, b + 1, sm.out1[o][1] * fac + ry);
        stf<F32>(out, b + 2, sm.out1[o][2] * fac + rz);
    }
}

__global__ __launch_bounds__(256)
void gttfn_kernel(const void* f0,  const void* f1,
                  const void* rbf, const void* gte,
                  const void* W1,  const void* b1,
                  const void* W2,  const void* b2,
                  const void* W3,  const void* b3,
                  const void* lg0, const void* lb0,
                  const void* lg1, const void* lb1,
                  const void* gW0, const void* gb0,
                  const void* gW1, const void* gb1,
                  const void* rW0, const void* rW1,
                  const void* nbr_v,
                  void* out)
{
    __shared__ Smem sm;
    __shared__ int flags[2];
    const int tid = threadIdx.x;

    if (tid < 64) {
        const u16* u = (const u16*)f0;
        unsigned short w = u[2 * tid];
        int e = (w >> 7) & 0xFF;
        bool garbage = (e >= 0x83) || (e <= 0x30);
        bool isF32 = __any(garbage);
        const int* ni = (const int*)nbr_v;
        bool hi_nonzero = (tid < 32) ? (ni[2 * tid + 1] != 0) : false;
        bool isI64 = !__any(hi_nonzero);
        if (tid == 0) { flags[0] = isF32 ? 1 : 0; flags[1] = isI64 ? 1 : 0; }
    }
    __syncthreads();
    int fF32 = flags[0], fI64 = flags[1];

    const int* nbr = (const int*)nbr_v;
    if (fF32) {
        if (fI64) gttfn_body<true, true >(sm, f0,f1,rbf,gte,W1,b1,W2,b2,W3,b3,lg0,lb0,lg1,lb1,gW0,gb0,gW1,gb1,rW0,rW1,nbr,out);
        else      gttfn_body<true, false>(sm, f0,f1,rbf,gte,W1,b1,W2,b2,W3,b3,lg0,lb0,lg1,lb1,gW0,gb0,gW1,gb1,rW0,rW1,nbr,out);
    } else {
        if (fI64) gttfn_body<false, true >(sm, f0,f1,rbf,gte,W1,b1,W2,b2,W3,b3,lg0,lb0,lg1,lb1,gW0,gb0,gW1,gb1,rW0,rW1,nbr,out);
        else      gttfn_body<false, false>(sm, f0,f1,rbf,gte,W1,b1,W2,b2,W3,b3,lg0,lb0,lg1,lb1,gW0,gb0,gW1,gb1,rW0,rW1,nbr,out);
    }
}

extern "C" void kernel_launch(void* const* d_in, const int* in_sizes, int n_in,
                              void* d_out, int out_size, void* d_ws, size_t ws_size,
                              hipStream_t stream) {
    gttfn_kernel<<<dim3(NNODES), dim3(256), 0, stream>>>(
        d_in[0],  d_in[1],  d_in[2],  d_in[3],
        d_in[4],  d_in[5],  d_in[6],  d_in[7],
        d_in[8],  d_in[9],  d_in[10], d_in[11],
        d_in[12], d_in[13], d_in[14], d_in[15],
        d_in[16], d_in[17], d_in[18], d_in[19],
        d_in[20], d_out);
}